// Round 10
// baseline (196.015 us; speedup 1.0000x reference)
//
#include <hip/hip_runtime.h>
#include <math.h>

// Problem constants (B=1 hardcoded).
#define M_TOT 8192
#define NXY   192
#define NPIX  (192*192)   // 36864
#define NC    8
#define REC   20          // floats per packed record (fp32 fallback path)

// GEMM: C[r=(y*8+c), n'=2x+{re,im}] = sum_k' A[r,k'] B[k',n']
//   A[r, 2m+{0,1}] = Re/Im( w[c,m]*Ey[m,y] )  -- computed in-kernel (fused)
//   BT[n'][k']: row 2x = (cos,-sin)(kx*gx); row 2x+1 = (sin,cos)(kx*gx)
#define GM 1536
#define GN 384
#define GK 16384
#define KSPLIT 32
#define KCHUNK (GK/KSPLIT)   // 512 k' = 256 m
#define BK 64                // k' per LDS step (32 m)
#define NSTEP (KCHUNK/BK)    // 8
#define BM 64                // 8 y * 8 c rows per tile
#define LDK 72               // padded LDS row stride (halves)

typedef _Float16 fp16;
typedef fp16 f16x8 __attribute__((ext_vector_type(8)));
typedef float f32x4 __attribute__((ext_vector_type(4)));

#define INV2PI 0.15915494309189535f

// ---------------------------------------------------------------------------
// pack_W: W[c*8192+m] = (kr*dc, ki*dc)  (float2, 512 KB)
// ---------------------------------------------------------------------------
__global__ __launch_bounds__(256) void pack_W(
    const float* __restrict__ kr, const float* __restrict__ ki,
    const float* __restrict__ dc, float2* __restrict__ W)
{
    int i = blockIdx.x * 256 + threadIdx.x;   // 65536
    int m = i & 8191;
    float d = dc[m];
    W[i] = make_float2(kr[i] * d, ki[i] * d);
}

// ---------------------------------------------------------------------------
// pack_B: BT[n'=2x+e][k'=2m+g]  (fp16 row-major, k fastest) — proven R7/R8.
// ---------------------------------------------------------------------------
__global__ __launch_bounds__(256) void pack_B_mfma(
    const float* __restrict__ traj, fp16* __restrict__ BT)
{
    int tid = blockIdx.x * 256 + threadIdx.x;   // 192*8192
    int x = tid >> 13;
    int m = tid & 8191;
    float kx = traj[m];
    float gx = (float)(x - 96);
    float r  = __builtin_amdgcn_fractf(kx * gx * INV2PI);
    float s  = __builtin_amdgcn_sinf(r);
    float c  = __builtin_amdgcn_cosf(r);
    unsigned int* B2 = (unsigned int*)BT;
    union { fp16 h[2]; unsigned int u; } p0, p1;
    p0.h[0] = (fp16)c;  p0.h[1] = (fp16)(-s);   // row 2x:   (c, -s)
    p1.h[0] = (fp16)s;  p1.h[1] = (fp16)c;      // row 2x+1: (s,  c)
    B2[(size_t)x * GK + m]          = p0.u;
    B2[(size_t)x * GK + (GK/2) + m] = p1.u;
}

// ---------------------------------------------------------------------------
// gemm_fused: BM=64 x BN=384 (full N), A computed in-kernel into LDS.
// grid = 768 (24 tm x 32 kz), 512 threads (8 waves, 2m x 4n).
// __launch_bounds__(512,4): VGPR cap 128 (acc[2][6]=48 f32 -> no spill; the
// R8 regression was acc spill under a 64-VGPR cap: VGPR_Count=64 < acc 72,
// +22MB scratch WRITE_SIZE).
// Same-kz blocks land on one XCD (bid%8 fixed) -> B chunk L2-resident.
// P (f16): [kz][GM][GN].
// ---------------------------------------------------------------------------
__global__ __launch_bounds__(512, 4) void gemm_fused(
    const float2* __restrict__ W, const float* __restrict__ traj,
    const fp16* __restrict__ BT, fp16* __restrict__ P)
{
    __shared__ __align__(16) fp16 a_s[BM][LDK];   //  9.2 KB
    __shared__ __align__(16) fp16 b_s[GN][LDK];   // 55.3 KB

    const int bid = blockIdx.x;
    const int u   = bid & 7;
    const int j   = bid >> 3;          // 0..95
    const int kz  = u + 8 * (j & 3);   // 0..31; same kz -> same XCD
    const int tm  = j >> 2;            // 0..23
    const int t   = threadIdx.x;

    // --- B staging: 6 x 16B segments per thread per step
    const int brow0 = t >> 3;          // 0..63
    const int bseg  = t & 7;           // 0..7
    const fp16* pB = BT + (size_t)kz * KCHUNK + bseg * 8;

    // --- A producer: threads t<256 -> (yl = t>>5 in 0..7, ml = t&31)
    const int yl = t >> 5;
    const int ml = t & 31;
    const bool aprod = (t < 256);
    const float gy = (float)(tm * 8 + yl - 96);

    // --- MFMA mapping (conventions proven in R7/R8 passing kernels)
    const int w_ = t >> 6, wm = w_ >> 2, wn = w_ & 3;   // 2m x 4n waves
    const int lane = t & 63, lr = lane & 15, lk = lane >> 4;

    f32x4 acc[2][6] = {};
    uint4 breg[6];

#define LOADB(ST)                                                          \
    _Pragma("unroll")                                                      \
    for (int i = 0; i < 6; ++i) {                                          \
        int rrow = i * 64 + brow0;                                         \
        breg[i] = *(const uint4*)(pB + (size_t)rrow * GK + (ST) * BK);     \
    }

    LOADB(0)

    for (int step = 0; step < NSTEP; ++step) {
        // ---- compute this step's A values (registers) ----
        unsigned int areg[NC];
        if (aprod) {
            int mg = kz * (KCHUNK/2) + step * (BK/2) + ml;   // global m
            float ky = traj[M_TOT + mg];
            float r  = __builtin_amdgcn_fractf(ky * gy * INV2PI);
            float sy = __builtin_amdgcn_sinf(r);
            float cy = __builtin_amdgcn_cosf(r);
#pragma unroll
            for (int c = 0; c < NC; ++c) {
                float2 wv = W[c * M_TOT + mg];
                union { fp16 h[2]; unsigned int u; } pk;
                pk.h[0] = (fp16)(wv.x * cy - wv.y * sy);   // Re(w*Ey)
                pk.h[1] = (fp16)(wv.x * sy + wv.y * cy);   // Im(w*Ey)
                areg[c] = pk.u;
            }
        }

        __syncthreads();            // previous step's LDS reads complete
#pragma unroll
        for (int i = 0; i < 6; ++i) {
            int rrow = i * 64 + brow0;
            *(uint4*)&b_s[rrow][bseg * 8] = breg[i];
        }
        if (aprod) {
#pragma unroll
            for (int c = 0; c < NC; ++c)
                *(unsigned int*)&a_s[yl * 8 + c][2 * ml] = areg[c];
        }
        __syncthreads();            // LDS tile visible

        if (step + 1 < NSTEP) { LOADB(step + 1) }   // prefetch overlaps MFMA

#pragma unroll
        for (int kk = 0; kk < 2; ++kk) {
            const int ko = kk * 32 + lk * 8;
            f16x8 af[2];
#pragma unroll
            for (int mi = 0; mi < 2; ++mi)
                af[mi] = *(const f16x8*)&a_s[wm * 32 + mi * 16 + lr][ko];
#pragma unroll
            for (int nj = 0; nj < 6; ++nj) {
                f16x8 bf = *(const f16x8*)&b_s[wn * 96 + nj * 16 + lr][ko];
#pragma unroll
                for (int mi = 0; mi < 2; ++mi)
                    acc[mi][nj] = __builtin_amdgcn_mfma_f32_16x16x32_f16(
                        af[mi], bf, acc[mi][nj], 0, 0, 0);
            }
        }
    }

    // ---- epilogue: f32 acc -> f16 partials ----
    fp16* Pz = P + (size_t)kz * GM * GN;
#pragma unroll
    for (int mi = 0; mi < 2; ++mi)
#pragma unroll
        for (int nj = 0; nj < 6; ++nj) {
            const int gcol = wn * 96 + nj * 16 + lr;
#pragma unroll
            for (int reg = 0; reg < 4; ++reg) {
                const int grow = tm * 64 + wm * 32 + mi * 16 + lk * 4 + reg;
                Pz[(size_t)grow * GN + gcol] = (fp16)acc[mi][nj][reg];
            }
        }
}

// ---------------------------------------------------------------------------
// combine2: reduce kz, coil-combine with conj(smaps), magnitude.
// 16x16 tiles, x = lane-fast so P reads are coalesced (R8 had it swapped).
// ---------------------------------------------------------------------------
__global__ __launch_bounds__(256) void combine2(
    const fp16* __restrict__ P,
    const float* __restrict__ smr, const float* __restrict__ smi,
    float* __restrict__ out)
{
    const int bid = blockIdx.x;                 // 144
    const int x = (bid % 12) * 16 + (threadIdx.x & 15);
    const int y = (bid / 12) * 16 + (threadIdx.x >> 4);
    const unsigned int* P32 = (const unsigned int*)P;   // half2 view

    float ore = 0.f, oim = 0.f;
#pragma unroll
    for (int c = 0; c < NC; ++c) {
        float re = 0.f, im = 0.f;
#pragma unroll
        for (int kz = 0; kz < KSPLIT; ++kz) {
            union { unsigned int u; fp16 h[2]; } v;
            v.u = P32[((size_t)kz * GM + y * 8 + c) * (GN/2) + x];
            re += (float)v.h[0];
            im += (float)v.h[1];
        }
        float sr = smr[c * NPIX + x * NXY + y];
        float si = smi[c * NPIX + x * NXY + y];
        ore += re * sr + im * si;               // * conj(smap)
        oim += im * sr - re * si;
    }
    out[x * NXY + y] = sqrtf(ore * ore + oim * oim);
}

// ===========================================================================
// fp32 fallback path (proven @328us) — used only if ws too small.
// ===========================================================================
__global__ __launch_bounds__(256) void pack_kernel(
    const float* __restrict__ kr, const float* __restrict__ ki,
    const float* __restrict__ traj, const float* __restrict__ dc,
    float* __restrict__ pack)
{
    int m = blockIdx.x * 256 + threadIdx.x;
    if (m >= M_TOT) return;
    float d = dc[m];
    float* r = pack + (size_t)m * REC;
#pragma unroll
    for (int c = 0; c < NC; ++c) {
        r[2*c]   = kr[c*M_TOT + m] * d;
        r[2*c+1] = ki[c*M_TOT + m] * d;
    }
    float ky = traj[M_TOT + m];
    r[16] = traj[m];
    r[17] = ky;
    r[18] = cosf(ky);
    r[19] = sinf(ky);
}

__global__ __launch_bounds__(256) void adj_main(
    const float* __restrict__ pack, float* __restrict__ partial, int mch)
{
    const int t = blockIdx.x * 256 + threadIdx.x;
    const int split = blockIdx.y;
    const int p0 = t * 2;
    const float gx  = (float)(p0 / NXY - NXY/2);
    const float gy0 = (float)(p0 % NXY - NXY/2);

    float2 par[NC], pai[NC];
#pragma unroll
    for (int c = 0; c < NC; ++c) {
        par[c] = make_float2(0.f, 0.f);
        pai[c] = make_float2(0.f, 0.f);
    }
    const float* rec = pack + (size_t)split * mch * REC;
    for (int m = 0; m < mch; ++m, rec += REC) {
        const float4* r4 = (const float4*)rec;
        float4 w01 = r4[0], w23 = r4[1], w45 = r4[2], w67 = r4[3], tkk = r4[4];
        float ph = fmaf(tkk.x, gx, tkk.y * gy0);
        float r  = __builtin_amdgcn_fractf(ph * INV2PI);
        float s0 = __builtin_amdgcn_sinf(r);
        float c0 = __builtin_amdgcn_cosf(r);
        float c1 = fmaf(c0, tkk.z, -(s0 * tkk.w));
        float s1 = fmaf(s0, tkk.z,  (c0 * tkk.w));
#define COIL(WR, WI, IDX)                                                \
        par[IDX].x = fmaf((WR), c0, fmaf(-(WI), s0, par[IDX].x));        \
        par[IDX].y = fmaf((WR), c1, fmaf(-(WI), s1, par[IDX].y));        \
        pai[IDX].x = fmaf((WR), s0, fmaf( (WI), c0, pai[IDX].x));        \
        pai[IDX].y = fmaf((WR), s1, fmaf( (WI), c1, pai[IDX].y));
        COIL(w01.x, w01.y, 0) COIL(w01.z, w01.w, 1)
        COIL(w23.x, w23.y, 2) COIL(w23.z, w23.w, 3)
        COIL(w45.x, w45.y, 4) COIL(w45.z, w45.w, 5)
        COIL(w67.x, w67.y, 6) COIL(w67.z, w67.w, 7)
#undef COIL
    }
#pragma unroll
    for (int c = 0; c < NC; ++c) {
        float4 v = make_float4(par[c].x, pai[c].x, par[c].y, pai[c].y);
        *(float4*)(partial + ((size_t)(split*NC + c)*NPIX + p0)*2) = v;
    }
}

__global__ __launch_bounds__(256) void combine_kernel(
    const float* __restrict__ partial,
    const float* __restrict__ smr, const float* __restrict__ smi,
    float* __restrict__ out, int nsplit)
{
    const int p = blockIdx.x * 256 + threadIdx.x;
    float cr[NC], ci[NC];
#pragma unroll
    for (int c = 0; c < NC; ++c) { cr[c] = 0.f; ci[c] = 0.f; }
    for (int s = 0; s < nsplit; ++s)
#pragma unroll
        for (int c = 0; c < NC; ++c) {
            float2 v = *(const float2*)(partial + ((size_t)(s*NC + c)*NPIX + p)*2);
            cr[c] += v.x; ci[c] += v.y;
        }
    float re = 0.f, im = 0.f;
#pragma unroll
    for (int c = 0; c < NC; ++c) {
        float sr = smr[c*NPIX + p];
        float si = smi[c*NPIX + p];
        re += cr[c]*sr + ci[c]*si;
        im += ci[c]*sr - cr[c]*si;
    }
    out[p] = sqrtf(re*re + im*im);
}

__global__ __launch_bounds__(256) void adj_fallback(
    const float* __restrict__ kr, const float* __restrict__ ki,
    const float* __restrict__ traj, const float* __restrict__ dc,
    const float* __restrict__ smr, const float* __restrict__ smi,
    float* __restrict__ out)
{
    const int p = blockIdx.x * 256 + threadIdx.x;
    const float gx = (float)(p / NXY - NXY/2);
    const float gy = (float)(p % NXY - NXY/2);
    float ar[NC], ai[NC];
#pragma unroll
    for (int c = 0; c < NC; ++c) { ar[c] = 0.f; ai[c] = 0.f; }
    for (int m = 0; m < M_TOT; ++m) {
        float kx = traj[m];
        float ky = traj[M_TOT + m];
        float d  = dc[m];
        float ph = fmaf(kx, gx, ky * gy);
        float r  = __builtin_amdgcn_fractf(ph * INV2PI);
        float s = __builtin_amdgcn_sinf(r);
        float c = __builtin_amdgcn_cosf(r);
#pragma unroll
        for (int cc = 0; cc < NC; ++cc) {
            float wr = kr[cc*M_TOT + m] * d;
            float wi = ki[cc*M_TOT + m] * d;
            ar[cc] = fmaf(wr, c, fmaf(-wi, s, ar[cc]));
            ai[cc] = fmaf(wr, s, fmaf( wi, c, ai[cc]));
        }
    }
    float re = 0.f, im = 0.f;
#pragma unroll
    for (int c = 0; c < NC; ++c) {
        float sr = smr[c*NPIX + p];
        float si = smi[c*NPIX + p];
        re += ar[c]*sr + ai[c]*si;
        im += ai[c]*sr - ar[c]*si;
    }
    out[p] = sqrtf(re*re + im*im);
}

// ---------------------------------------------------------------------------
extern "C" void kernel_launch(void* const* d_in, const int* in_sizes, int n_in,
                              void* d_out, int out_size, void* d_ws, size_t ws_size,
                              hipStream_t stream)
{
    const float* kr   = (const float*)d_in[0];
    const float* ki   = (const float*)d_in[1];
    const float* traj = (const float*)d_in[2];
    const float* smr  = (const float*)d_in[3];
    const float* smi  = (const float*)d_in[4];
    const float* dc   = (const float*)d_in[5];
    float* out = (float*)d_out;

    const size_t B_bytes = (size_t)GN * GK * sizeof(fp16);            // 12.58 MB
    const size_t P_bytes = (size_t)KSPLIT * GM * GN * sizeof(fp16);   // 37.75 MB
    const size_t W_bytes = (size_t)NC * M_TOT * sizeof(float2);       // 0.5 MB
    const size_t need_mfma = B_bytes + P_bytes + W_bytes;             // ~50.8 MB

    if (ws_size >= need_mfma) {
        fp16*   BT = (fp16*)d_ws;
        fp16*   P  = (fp16*)((char*)d_ws + B_bytes);
        float2* W  = (float2*)((char*)d_ws + B_bytes + P_bytes);
        pack_W<<<(NC*M_TOT)/256, 256, 0, stream>>>(kr, ki, dc, W);
        pack_B_mfma<<<(NXY*M_TOT)/256, 256, 0, stream>>>(traj, BT);
        gemm_fused<<<(GM/BM)*KSPLIT, 512, 0, stream>>>(W, traj, BT, P);
        combine2<<<NPIX/256, 256, 0, stream>>>(P, smr, smi, out);
        return;
    }

    const size_t pack_bytes = (size_t)M_TOT * REC * sizeof(float);
    int split = 0;
    for (int s = 32; s >= 8; s >>= 1) {
        size_t need = pack_bytes + (size_t)s * NC * NPIX * 2 * sizeof(float);
        if (ws_size >= need) { split = s; break; }
    }
    if (split > 0) {
        float* pack    = (float*)d_ws;
        float* partial = pack + (size_t)M_TOT * REC;
        int mch = M_TOT / split;
        pack_kernel<<<(M_TOT + 255)/256, 256, 0, stream>>>(kr, ki, traj, dc, pack);
        adj_main<<<dim3(NPIX/2/256, split), 256, 0, stream>>>(pack, partial, mch);
        combine_kernel<<<NPIX/256, 256, 0, stream>>>(partial, smr, smi, out, split);
    } else {
        adj_fallback<<<NPIX/256, 256, 0, stream>>>(kr, ki, traj, dc, smr, smi, out);
    }
}

// Round 11
// 186.913 us; speedup vs baseline: 1.0487x; 1.0487x over previous
//
#include <hip/hip_runtime.h>
#include <math.h>

// Problem constants (B=1 hardcoded).
#define M_TOT 8192
#define NXY   192
#define NPIX  (192*192)   // 36864
#define NC    8
#define REC   20          // floats per packed record (fp32 fallback path)

// GEMM: C[r=(y*8+c), n'=2x+{re,im}] = sum_k' A[r,k'] B[k',n']
//   A[r, 2m+{0,1}] = Re/Im( w[c,m]*Ey[m,y] )  -- computed in-kernel (fused)
//   BT[n'][k']: row 2x = (cos,-sin)(kx*gx); row 2x+1 = (sin,cos)(kx*gx)
#define GM 1536
#define GN 384
#define GK 16384
#define KSPLIT 32
#define KCHUNK (GK/KSPLIT)   // 512 k' = 256 m
#define BK 64                // k' per LDS step (32 m)
#define NSTEP (KCHUNK/BK)    // 8
#define BM 64                // 8 y * 8 c rows per tile
#define LDK 72               // padded LDS row stride (halves)

typedef _Float16 fp16;
typedef fp16 f16x8 __attribute__((ext_vector_type(8)));
typedef float f32x4 __attribute__((ext_vector_type(4)));

#define INV2PI 0.15915494309189535f

// ---------------------------------------------------------------------------
// pack_W: W[c*8192+m] = (kr*dc, ki*dc)  (float2, 512 KB)
// ---------------------------------------------------------------------------
__global__ __launch_bounds__(256) void pack_W(
    const float* __restrict__ kr, const float* __restrict__ ki,
    const float* __restrict__ dc, float2* __restrict__ W)
{
    int i = blockIdx.x * 256 + threadIdx.x;   // 65536
    int m = i & 8191;
    float d = dc[m];
    W[i] = make_float2(kr[i] * d, ki[i] * d);
}

// ---------------------------------------------------------------------------
// pack_B: BT[n'=2x+e][k'=2m+g]  (fp16 row-major, k fastest) — proven R7/R8.
// ---------------------------------------------------------------------------
__global__ __launch_bounds__(256) void pack_B_mfma(
    const float* __restrict__ traj, fp16* __restrict__ BT)
{
    int tid = blockIdx.x * 256 + threadIdx.x;   // 192*8192
    int x = tid >> 13;
    int m = tid & 8191;
    float kx = traj[m];
    float gx = (float)(x - 96);
    float r  = __builtin_amdgcn_fractf(kx * gx * INV2PI);
    float s  = __builtin_amdgcn_sinf(r);
    float c  = __builtin_amdgcn_cosf(r);
    unsigned int* B2 = (unsigned int*)BT;
    union { fp16 h[2]; unsigned int u; } p0, p1;
    p0.h[0] = (fp16)c;  p0.h[1] = (fp16)(-s);   // row 2x:   (c, -s)
    p1.h[0] = (fp16)s;  p1.h[1] = (fp16)c;      // row 2x+1: (s,  c)
    B2[(size_t)x * GK + m]          = p0.u;
    B2[(size_t)x * GK + (GK/2) + m] = p1.u;
}

// ---------------------------------------------------------------------------
// gemm_fused: BM=64 x BN=384 (full N), A computed in-kernel into LDS.
// grid = 768 (24 tm x 32 kz), 512 threads (8 waves, 2m x 4n).
// __launch_bounds__(512, 2): gfx950 has a UNIFIED VGPR/AGPR file — the R10
// failure was (512,4) capping arch+acc at 128/wave (64 VGPR + 64 AGPR acc),
// spilling the working set (WRITE_SIZE 297MB of scratch, MfmaUtil 7%).
// (512,2) -> 256 combined cap: 64 AGPR acc + ~110 arch VGPR, no spill.
// Same-kz blocks land on one XCD (bid%8 fixed) -> B chunk L2-resident.
// P (f16): [kz][GM][GN].
// ---------------------------------------------------------------------------
__global__ __launch_bounds__(512, 2) void gemm_fused(
    const float2* __restrict__ W, const float* __restrict__ traj,
    const fp16* __restrict__ BT, fp16* __restrict__ P)
{
    __shared__ __align__(16) fp16 a_s[BM][LDK];   //  9.2 KB
    __shared__ __align__(16) fp16 b_s[GN][LDK];   // 55.3 KB

    const int bid = blockIdx.x;
    const int u   = bid & 7;
    const int j   = bid >> 3;          // 0..95
    const int kz  = u + 8 * (j & 3);   // 0..31; same kz -> same XCD
    const int tm  = j >> 2;            // 0..23
    const int t   = threadIdx.x;

    // --- B staging: 6 x 16B segments per thread per step
    const int brow0 = t >> 3;          // 0..63
    const int bseg  = t & 7;           // 0..7
    const fp16* pB = BT + (size_t)kz * KCHUNK + bseg * 8;

    // --- A producer: threads t<256 -> (yl = t>>5 in 0..7, ml = t&31)
    const int yl = t >> 5;
    const int ml = t & 31;
    const bool aprod = (t < 256);
    const float gy = (float)(tm * 8 + yl - 96);

    // --- MFMA mapping (conventions proven in R7/R8 passing kernels)
    const int w_ = t >> 6, wm = w_ >> 2, wn = w_ & 3;   // 2m x 4n waves
    const int lane = t & 63, lr = lane & 15, lk = lane >> 4;

    f32x4 acc[2][6] = {};
    uint4 breg[6];

#define LOADB(ST)                                                          \
    _Pragma("unroll")                                                      \
    for (int i = 0; i < 6; ++i) {                                          \
        int rrow = i * 64 + brow0;                                         \
        breg[i] = *(const uint4*)(pB + (size_t)rrow * GK + (ST) * BK);     \
    }

    LOADB(0)

    for (int step = 0; step < NSTEP; ++step) {
        // ---- compute this step's A values (registers) ----
        unsigned int areg[NC];
        if (aprod) {
            int mg = kz * (KCHUNK/2) + step * (BK/2) + ml;   // global m
            float ky = traj[M_TOT + mg];
            float r  = __builtin_amdgcn_fractf(ky * gy * INV2PI);
            float sy = __builtin_amdgcn_sinf(r);
            float cy = __builtin_amdgcn_cosf(r);
#pragma unroll
            for (int c = 0; c < NC; ++c) {
                float2 wv = W[c * M_TOT + mg];
                union { fp16 h[2]; unsigned int u; } pk;
                pk.h[0] = (fp16)(wv.x * cy - wv.y * sy);   // Re(w*Ey)
                pk.h[1] = (fp16)(wv.x * sy + wv.y * cy);   // Im(w*Ey)
                areg[c] = pk.u;
            }
        }

        __syncthreads();            // previous step's LDS reads complete
#pragma unroll
        for (int i = 0; i < 6; ++i) {
            int rrow = i * 64 + brow0;
            *(uint4*)&b_s[rrow][bseg * 8] = breg[i];
        }
        if (aprod) {
#pragma unroll
            for (int c = 0; c < NC; ++c)
                *(unsigned int*)&a_s[yl * 8 + c][2 * ml] = areg[c];
        }
        __syncthreads();            // LDS tile visible

        if (step + 1 < NSTEP) { LOADB(step + 1) }   // prefetch overlaps MFMA

#pragma unroll
        for (int kk = 0; kk < 2; ++kk) {
            const int ko = kk * 32 + lk * 8;
            f16x8 af[2];
#pragma unroll
            for (int mi = 0; mi < 2; ++mi)
                af[mi] = *(const f16x8*)&a_s[wm * 32 + mi * 16 + lr][ko];
#pragma unroll
            for (int nj = 0; nj < 6; ++nj) {
                f16x8 bf = *(const f16x8*)&b_s[wn * 96 + nj * 16 + lr][ko];
#pragma unroll
                for (int mi = 0; mi < 2; ++mi)
                    acc[mi][nj] = __builtin_amdgcn_mfma_f32_16x16x32_f16(
                        af[mi], bf, acc[mi][nj], 0, 0, 0);
            }
        }
    }

    // ---- epilogue: f32 acc -> f16 partials ----
    fp16* Pz = P + (size_t)kz * GM * GN;
#pragma unroll
    for (int mi = 0; mi < 2; ++mi)
#pragma unroll
        for (int nj = 0; nj < 6; ++nj) {
            const int gcol = wn * 96 + nj * 16 + lr;
#pragma unroll
            for (int reg = 0; reg < 4; ++reg) {
                const int grow = tm * 64 + wm * 32 + mi * 16 + lk * 4 + reg;
                Pz[(size_t)grow * GN + gcol] = (fp16)acc[mi][nj][reg];
            }
        }
}

// ---------------------------------------------------------------------------
// combine2: reduce kz, coil-combine with conj(smaps), magnitude.
// 16x16 tiles, x = lane-fast so P reads are coalesced.
// ---------------------------------------------------------------------------
__global__ __launch_bounds__(256) void combine2(
    const fp16* __restrict__ P,
    const float* __restrict__ smr, const float* __restrict__ smi,
    float* __restrict__ out)
{
    const int bid = blockIdx.x;                 // 144
    const int x = (bid % 12) * 16 + (threadIdx.x & 15);
    const int y = (bid / 12) * 16 + (threadIdx.x >> 4);
    const unsigned int* P32 = (const unsigned int*)P;   // half2 view

    float ore = 0.f, oim = 0.f;
#pragma unroll
    for (int c = 0; c < NC; ++c) {
        float re = 0.f, im = 0.f;
#pragma unroll
        for (int kz = 0; kz < KSPLIT; ++kz) {
            union { unsigned int u; fp16 h[2]; } v;
            v.u = P32[((size_t)kz * GM + y * 8 + c) * (GN/2) + x];
            re += (float)v.h[0];
            im += (float)v.h[1];
        }
        float sr = smr[c * NPIX + x * NXY + y];
        float si = smi[c * NPIX + x * NXY + y];
        ore += re * sr + im * si;               // * conj(smap)
        oim += im * sr - re * si;
    }
    out[x * NXY + y] = sqrtf(ore * ore + oim * oim);
}

// ===========================================================================
// fp32 fallback path (proven @328us) — used only if ws too small.
// ===========================================================================
__global__ __launch_bounds__(256) void pack_kernel(
    const float* __restrict__ kr, const float* __restrict__ ki,
    const float* __restrict__ traj, const float* __restrict__ dc,
    float* __restrict__ pack)
{
    int m = blockIdx.x * 256 + threadIdx.x;
    if (m >= M_TOT) return;
    float d = dc[m];
    float* r = pack + (size_t)m * REC;
#pragma unroll
    for (int c = 0; c < NC; ++c) {
        r[2*c]   = kr[c*M_TOT + m] * d;
        r[2*c+1] = ki[c*M_TOT + m] * d;
    }
    float ky = traj[M_TOT + m];
    r[16] = traj[m];
    r[17] = ky;
    r[18] = cosf(ky);
    r[19] = sinf(ky);
}

__global__ __launch_bounds__(256) void adj_main(
    const float* __restrict__ pack, float* __restrict__ partial, int mch)
{
    const int t = blockIdx.x * 256 + threadIdx.x;
    const int split = blockIdx.y;
    const int p0 = t * 2;
    const float gx  = (float)(p0 / NXY - NXY/2);
    const float gy0 = (float)(p0 % NXY - NXY/2);

    float2 par[NC], pai[NC];
#pragma unroll
    for (int c = 0; c < NC; ++c) {
        par[c] = make_float2(0.f, 0.f);
        pai[c] = make_float2(0.f, 0.f);
    }
    const float* rec = pack + (size_t)split * mch * REC;
    for (int m = 0; m < mch; ++m, rec += REC) {
        const float4* r4 = (const float4*)rec;
        float4 w01 = r4[0], w23 = r4[1], w45 = r4[2], w67 = r4[3], tkk = r4[4];
        float ph = fmaf(tkk.x, gx, tkk.y * gy0);
        float r  = __builtin_amdgcn_fractf(ph * INV2PI);
        float s0 = __builtin_amdgcn_sinf(r);
        float c0 = __builtin_amdgcn_cosf(r);
        float c1 = fmaf(c0, tkk.z, -(s0 * tkk.w));
        float s1 = fmaf(s0, tkk.z,  (c0 * tkk.w));
#define COIL(WR, WI, IDX)                                                \
        par[IDX].x = fmaf((WR), c0, fmaf(-(WI), s0, par[IDX].x));        \
        par[IDX].y = fmaf((WR), c1, fmaf(-(WI), s1, par[IDX].y));        \
        pai[IDX].x = fmaf((WR), s0, fmaf( (WI), c0, pai[IDX].x));        \
        pai[IDX].y = fmaf((WR), s1, fmaf( (WI), c1, pai[IDX].y));
        COIL(w01.x, w01.y, 0) COIL(w01.z, w01.w, 1)
        COIL(w23.x, w23.y, 2) COIL(w23.z, w23.w, 3)
        COIL(w45.x, w45.y, 4) COIL(w45.z, w45.w, 5)
        COIL(w67.x, w67.y, 6) COIL(w67.z, w67.w, 7)
#undef COIL
    }
#pragma unroll
    for (int c = 0; c < NC; ++c) {
        float4 v = make_float4(par[c].x, pai[c].x, par[c].y, pai[c].y);
        *(float4*)(partial + ((size_t)(split*NC + c)*NPIX + p0)*2) = v;
    }
}

__global__ __launch_bounds__(256) void combine_kernel(
    const float* __restrict__ partial,
    const float* __restrict__ smr, const float* __restrict__ smi,
    float* __restrict__ out, int nsplit)
{
    const int p = blockIdx.x * 256 + threadIdx.x;
    float cr[NC], ci[NC];
#pragma unroll
    for (int c = 0; c < NC; ++c) { cr[c] = 0.f; ci[c] = 0.f; }
    for (int s = 0; s < nsplit; ++s)
#pragma unroll
        for (int c = 0; c < NC; ++c) {
            float2 v = *(const float2*)(partial + ((size_t)(s*NC + c)*NPIX + p)*2);
            cr[c] += v.x; ci[c] += v.y;
        }
    float re = 0.f, im = 0.f;
#pragma unroll
    for (int c = 0; c < NC; ++c) {
        float sr = smr[c*NPIX + p];
        float si = smi[c*NPIX + p];
        re += cr[c]*sr + ci[c]*si;
        im += ci[c]*sr - cr[c]*si;
    }
    out[p] = sqrtf(re*re + im*im);
}

__global__ __launch_bounds__(256) void adj_fallback(
    const float* __restrict__ kr, const float* __restrict__ ki,
    const float* __restrict__ traj, const float* __restrict__ dc,
    const float* __restrict__ smr, const float* __restrict__ smi,
    float* __restrict__ out)
{
    const int p = blockIdx.x * 256 + threadIdx.x;
    const float gx = (float)(p / NXY - NXY/2);
    const float gy = (float)(p % NXY - NXY/2);
    float ar[NC], ai[NC];
#pragma unroll
    for (int c = 0; c < NC; ++c) { ar[c] = 0.f; ai[c] = 0.f; }
    for (int m = 0; m < M_TOT; ++m) {
        float kx = traj[m];
        float ky = traj[M_TOT + m];
        float d  = dc[m];
        float ph = fmaf(kx, gx, ky * gy);
        float r  = __builtin_amdgcn_fractf(ph * INV2PI);
        float s = __builtin_amdgcn_sinf(r);
        float c = __builtin_amdgcn_cosf(r);
#pragma unroll
        for (int cc = 0; cc < NC; ++cc) {
            float wr = kr[cc*M_TOT + m] * d;
            float wi = ki[cc*M_TOT + m] * d;
            ar[cc] = fmaf(wr, c, fmaf(-wi, s, ar[cc]));
            ai[cc] = fmaf(wr, s, fmaf( wi, c, ai[cc]));
        }
    }
    float re = 0.f, im = 0.f;
#pragma unroll
    for (int c = 0; c < NC; ++c) {
        float sr = smr[c*NPIX + p];
        float si = smi[c*NPIX + p];
        re += ar[c]*sr + ai[c]*si;
        im += ai[c]*sr - ar[c]*si;
    }
    out[p] = sqrtf(re*re + im*im);
}

// ---------------------------------------------------------------------------
extern "C" void kernel_launch(void* const* d_in, const int* in_sizes, int n_in,
                              void* d_out, int out_size, void* d_ws, size_t ws_size,
                              hipStream_t stream)
{
    const float* kr   = (const float*)d_in[0];
    const float* ki   = (const float*)d_in[1];
    const float* traj = (const float*)d_in[2];
    const float* smr  = (const float*)d_in[3];
    const float* smi  = (const float*)d_in[4];
    const float* dc   = (const float*)d_in[5];
    float* out = (float*)d_out;

    const size_t B_bytes = (size_t)GN * GK * sizeof(fp16);            // 12.58 MB
    const size_t P_bytes = (size_t)KSPLIT * GM * GN * sizeof(fp16);   // 37.75 MB
    const size_t W_bytes = (size_t)NC * M_TOT * sizeof(float2);       // 0.5 MB
    const size_t need_mfma = B_bytes + P_bytes + W_bytes;             // ~50.8 MB

    if (ws_size >= need_mfma) {
        fp16*   BT = (fp16*)d_ws;
        fp16*   P  = (fp16*)((char*)d_ws + B_bytes);
        float2* W  = (float2*)((char*)d_ws + B_bytes + P_bytes);
        pack_W<<<(NC*M_TOT)/256, 256, 0, stream>>>(kr, ki, dc, W);
        pack_B_mfma<<<(NXY*M_TOT)/256, 256, 0, stream>>>(traj, BT);
        gemm_fused<<<(GM/BM)*KSPLIT, 512, 0, stream>>>(W, traj, BT, P);
        combine2<<<NPIX/256, 256, 0, stream>>>(P, smr, smi, out);
        return;
    }

    const size_t pack_bytes = (size_t)M_TOT * REC * sizeof(float);
    int split = 0;
    for (int s = 32; s >= 8; s >>= 1) {
        size_t need = pack_bytes + (size_t)s * NC * NPIX * 2 * sizeof(float);
        if (ws_size >= need) { split = s; break; }
    }
    if (split > 0) {
        float* pack    = (float*)d_ws;
        float* partial = pack + (size_t)M_TOT * REC;
        int mch = M_TOT / split;
        pack_kernel<<<(M_TOT + 255)/256, 256, 0, stream>>>(kr, ki, traj, dc, pack);
        adj_main<<<dim3(NPIX/2/256, split), 256, 0, stream>>>(pack, partial, mch);
        combine_kernel<<<NPIX/256, 256, 0, stream>>>(partial, smr, smi, out, split);
    } else {
        adj_fallback<<<NPIX/256, 256, 0, stream>>>(kr, ki, traj, dc, smr, smi, out);
    }
}

// Round 13
// 128.812 us; speedup vs baseline: 1.5217x; 1.4511x over previous
//
#include <hip/hip_runtime.h>
#include <math.h>

// Problem constants (B=1 hardcoded).
#define M_TOT 8192
#define NXY   192
#define NPIX  (192*192)   // 36864
#define NC    8
#define REC   20          // floats per packed record (fp32 fallback path)

// GEMM: C[r=(y*8+c), n'=2x+{re,im}] = sum_k' A[r,k'] B[k',n']
//   A[r, 2m+{0,1}] = Re/Im( (kspace*dc)[c,m] * Ey[m,y] )  -- fused in-kernel
//   BT[n'][k']: row 2x = (cos,-sin)(kx*gx); row 2x+1 = (sin,cos)(kx*gx)
#define GM 1536
#define GN 384
#define GK 16384
#define KSPLIT 32
#define KCHUNK (GK/KSPLIT)   // 512 k' = 256 m
#define BK 64                // k' per LDS step (32 m)
#define NSTEP (KCHUNK/BK)    // 8
#define BM 64                // 8 y * 8 c rows per tile
#define LDK 72               // padded LDS row stride (halves)

typedef _Float16 fp16;
typedef fp16 f16x8 __attribute__((ext_vector_type(8)));
typedef float f32x4 __attribute__((ext_vector_type(4)));

#define INV2PI 0.15915494309189535f

// ---------------------------------------------------------------------------
// pack_B: BT[n'=2x+e][k'=2m+g]  (fp16 row-major, k fastest) — proven R7-R11.
// ---------------------------------------------------------------------------
__global__ __launch_bounds__(256) void pack_B_mfma(
    const float* __restrict__ traj, fp16* __restrict__ BT)
{
    int tid = blockIdx.x * 256 + threadIdx.x;   // 192*8192
    int x = tid >> 13;
    int m = tid & 8191;
    float kx = traj[m];
    float gx = (float)(x - 96);
    float r  = __builtin_amdgcn_fractf(kx * gx * INV2PI);
    float s  = __builtin_amdgcn_sinf(r);
    float c  = __builtin_amdgcn_cosf(r);
    unsigned int* B2 = (unsigned int*)BT;
    union { fp16 h[2]; unsigned int u; } p0, p1;
    p0.h[0] = (fp16)c;  p0.h[1] = (fp16)(-s);   // row 2x:   (c, -s)
    p1.h[0] = (fp16)s;  p1.h[1] = (fp16)c;      // row 2x+1: (s,  c)
    B2[(size_t)x * GK + m]          = p0.u;
    B2[(size_t)x * GK + (GK/2) + m] = p1.u;
}

// ---------------------------------------------------------------------------
// gemm_fused: BM=64 x BN=384 (full N), A computed in-kernel into LDS.
// grid = 768 (24 tm x 32 kz), 512 threads (8 waves, 2m x 4n).
//
// R10/R11 lesson: cross-barrier register live ranges (prefetched breg/areg)
// were scratch-spilled (~250MB WRITE_SIZE, MfmaUtil 7%) and launch_bounds
// hints did not move the allocator (VGPR_Count pinned at 64 both tries).
// This version keeps ALL staging registers phase-local: 2-barrier loop,
// load+write inside the same phase, no prefetch. Peak arch-VGPR ~60/phase.
// dc/kspace scaling folded in here (pack_W kernel removed).
// Same-kz blocks land on one XCD (bid%8 fixed) -> B chunk L2-resident.
// P (f16): [kz][GM][GN].
// ---------------------------------------------------------------------------
__global__ __launch_bounds__(512) void gemm_fused(
    const float* __restrict__ kr, const float* __restrict__ ki,
    const float* __restrict__ dc, const float* __restrict__ traj,
    const fp16* __restrict__ BT, fp16* __restrict__ P)
{
    __shared__ __align__(16) fp16 a_s[BM][LDK];   //  9.2 KB
    __shared__ __align__(16) fp16 b_s[GN][LDK];   // 55.3 KB  (total 63 KB -> 2 blocks/CU)

    const int bid = blockIdx.x;
    const int u   = bid & 7;
    const int j   = bid >> 3;          // 0..95
    const int kz  = u + 8 * (j & 3);   // 0..31; same kz -> same XCD
    const int tm  = j >> 2;            // 0..23
    const int t   = threadIdx.x;

    // --- B staging: 6 x 16B segments per thread per step
    const int brow0 = t >> 3;          // 0..63
    const int bseg  = t & 7;           // 0..7
    const fp16* pB = BT + (size_t)kz * KCHUNK + bseg * 8;

    // --- A producer: threads t<256 -> (yl = t>>5 in 0..7, ml = t&31)
    const int yl = t >> 5;
    const int ml = t & 31;
    const bool aprod = (t < 256);
    const float gy = (float)(tm * 8 + yl - 96);

    // --- MFMA mapping (conventions proven since R7)
    const int w_ = t >> 6, wm = w_ >> 2, wn = w_ & 3;   // 2m x 4n waves
    const int lane = t & 63, lr = lane & 15, lk = lane >> 4;

    f32x4 acc[2][6] = {};

    for (int step = 0; step < NSTEP; ++step) {
        __syncthreads();            // previous step's LDS reads complete

        // ---- B stage: load global -> reg -> LDS, all within this phase ----
        {
            uint4 breg[6];
#pragma unroll
            for (int i = 0; i < 6; ++i) {
                int rrow = i * 64 + brow0;
                breg[i] = *(const uint4*)(pB + (size_t)rrow * GK + step * BK);
            }
#pragma unroll
            for (int i = 0; i < 6; ++i) {
                int rrow = i * 64 + brow0;
                *(uint4*)&b_s[rrow][bseg * 8] = breg[i];
            }
        }

        // ---- A stage: produce (sincos + rotation) and write, same phase ----
        if (aprod) {
            int mg = kz * (KCHUNK/2) + step * (BK/2) + ml;   // global m
            float ky = traj[M_TOT + mg];
            float d  = dc[mg];
            float r  = __builtin_amdgcn_fractf(ky * gy * INV2PI);
            float sy = __builtin_amdgcn_sinf(r);
            float cy = __builtin_amdgcn_cosf(r);
#pragma unroll
            for (int c = 0; c < NC; ++c) {
                float wr = kr[c * M_TOT + mg] * d;
                float wi = ki[c * M_TOT + mg] * d;
                union { fp16 h[2]; unsigned int u; } pk;
                pk.h[0] = (fp16)(wr * cy - wi * sy);   // Re(w*Ey)
                pk.h[1] = (fp16)(wr * sy + wi * cy);   // Im(w*Ey)
                *(unsigned int*)&a_s[yl * 8 + c][2 * ml] = pk.u;
            }
        }

        __syncthreads();            // LDS tile visible

        // ---- MFMA cluster (register-only besides LDS fragment reads) ----
#pragma unroll
        for (int kk = 0; kk < 2; ++kk) {
            const int ko = kk * 32 + lk * 8;
            f16x8 af[2];
#pragma unroll
            for (int mi = 0; mi < 2; ++mi)
                af[mi] = *(const f16x8*)&a_s[wm * 32 + mi * 16 + lr][ko];
#pragma unroll
            for (int nj = 0; nj < 6; ++nj) {
                f16x8 bf = *(const f16x8*)&b_s[wn * 96 + nj * 16 + lr][ko];
#pragma unroll
                for (int mi = 0; mi < 2; ++mi)
                    acc[mi][nj] = __builtin_amdgcn_mfma_f32_16x16x32_f16(
                        af[mi], bf, acc[mi][nj], 0, 0, 0);
            }
        }
    }

    // ---- epilogue: f32 acc -> f16 partials ----
    fp16* Pz = P + (size_t)kz * GM * GN;
#pragma unroll
    for (int mi = 0; mi < 2; ++mi)
#pragma unroll
        for (int nj = 0; nj < 6; ++nj) {
            const int gcol = wn * 96 + nj * 16 + lr;
#pragma unroll
            for (int reg = 0; reg < 4; ++reg) {
                const int grow = tm * 64 + wm * 32 + mi * 16 + lk * 4 + reg;
                Pz[(size_t)grow * GN + gcol] = (fp16)acc[mi][nj][reg];
            }
        }
}

// ---------------------------------------------------------------------------
// combine2: reduce kz, coil-combine with conj(smaps), magnitude.
// 16x16 tiles, x = lane-fast so P reads are coalesced.
// ---------------------------------------------------------------------------
__global__ __launch_bounds__(256) void combine2(
    const fp16* __restrict__ P,
    const float* __restrict__ smr, const float* __restrict__ smi,
    float* __restrict__ out)
{
    const int bid = blockIdx.x;                 // 144
    const int x = (bid % 12) * 16 + (threadIdx.x & 15);
    const int y = (bid / 12) * 16 + (threadIdx.x >> 4);
    const unsigned int* P32 = (const unsigned int*)P;   // half2 view

    float ore = 0.f, oim = 0.f;
#pragma unroll
    for (int c = 0; c < NC; ++c) {
        float re = 0.f, im = 0.f;
#pragma unroll
        for (int kz = 0; kz < KSPLIT; ++kz) {
            union { unsigned int u; fp16 h[2]; } v;
            v.u = P32[((size_t)kz * GM + y * 8 + c) * (GN/2) + x];
            re += (float)v.h[0];
            im += (float)v.h[1];
        }
        float sr = smr[c * NPIX + x * NXY + y];
        float si = smi[c * NPIX + x * NXY + y];
        ore += re * sr + im * si;               // * conj(smap)
        oim += im * sr - re * si;
    }
    out[x * NXY + y] = sqrtf(ore * ore + oim * oim);
}

// ===========================================================================
// fp32 fallback path (proven @328us) — used only if ws too small.
// ===========================================================================
__global__ __launch_bounds__(256) void pack_kernel(
    const float* __restrict__ kr, const float* __restrict__ ki,
    const float* __restrict__ traj, const float* __restrict__ dc,
    float* __restrict__ pack)
{
    int m = blockIdx.x * 256 + threadIdx.x;
    if (m >= M_TOT) return;
    float d = dc[m];
    float* r = pack + (size_t)m * REC;
#pragma unroll
    for (int c = 0; c < NC; ++c) {
        r[2*c]   = kr[c*M_TOT + m] * d;
        r[2*c+1] = ki[c*M_TOT + m] * d;
    }
    float ky = traj[M_TOT + m];
    r[16] = traj[m];
    r[17] = ky;
    r[18] = cosf(ky);
    r[19] = sinf(ky);
}

__global__ __launch_bounds__(256) void adj_main(
    const float* __restrict__ pack, float* __restrict__ partial, int mch)
{
    const int t = blockIdx.x * 256 + threadIdx.x;
    const int split = blockIdx.y;
    const int p0 = t * 2;
    const float gx  = (float)(p0 / NXY - NXY/2);
    const float gy0 = (float)(p0 % NXY - NXY/2);

    float2 par[NC], pai[NC];
#pragma unroll
    for (int c = 0; c < NC; ++c) {
        par[c] = make_float2(0.f, 0.f);
        pai[c] = make_float2(0.f, 0.f);
    }
    const float* rec = pack + (size_t)split * mch * REC;
    for (int m = 0; m < mch; ++m, rec += REC) {
        const float4* r4 = (const float4*)rec;
        float4 w01 = r4[0], w23 = r4[1], w45 = r4[2], w67 = r4[3], tkk = r4[4];
        float ph = fmaf(tkk.x, gx, tkk.y * gy0);
        float r  = __builtin_amdgcn_fractf(ph * INV2PI);
        float s0 = __builtin_amdgcn_sinf(r);
        float c0 = __builtin_amdgcn_cosf(r);
        float c1 = fmaf(c0, tkk.z, -(s0 * tkk.w));
        float s1 = fmaf(s0, tkk.z,  (c0 * tkk.w));
#define COIL(WR, WI, IDX)                                                \
        par[IDX].x = fmaf((WR), c0, fmaf(-(WI), s0, par[IDX].x));        \
        par[IDX].y = fmaf((WR), c1, fmaf(-(WI), s1, par[IDX].y));        \
        pai[IDX].x = fmaf((WR), s0, fmaf( (WI), c0, pai[IDX].x));        \
        pai[IDX].y = fmaf((WR), s1, fmaf( (WI), c1, pai[IDX].y));
        COIL(w01.x, w01.y, 0) COIL(w01.z, w01.w, 1)
        COIL(w23.x, w23.y, 2) COIL(w23.z, w23.w, 3)
        COIL(w45.x, w45.y, 4) COIL(w45.z, w45.w, 5)
        COIL(w67.x, w67.y, 6) COIL(w67.z, w67.w, 7)
#undef COIL
    }
#pragma unroll
    for (int c = 0; c < NC; ++c) {
        float4 v = make_float4(par[c].x, pai[c].x, par[c].y, pai[c].y);
        *(float4*)(partial + ((size_t)(split*NC + c)*NPIX + p0)*2) = v;
    }
}

__global__ __launch_bounds__(256) void combine_kernel(
    const float* __restrict__ partial,
    const float* __restrict__ smr, const float* __restrict__ smi,
    float* __restrict__ out, int nsplit)
{
    const int p = blockIdx.x * 256 + threadIdx.x;
    float cr[NC], ci[NC];
#pragma unroll
    for (int c = 0; c < NC; ++c) { cr[c] = 0.f; ci[c] = 0.f; }
    for (int s = 0; s < nsplit; ++s)
#pragma unroll
        for (int c = 0; c < NC; ++c) {
            float2 v = *(const float2*)(partial + ((size_t)(s*NC + c)*NPIX + p)*2);
            cr[c] += v.x; ci[c] += v.y;
        }
    float re = 0.f, im = 0.f;
#pragma unroll
    for (int c = 0; c < NC; ++c) {
        float sr = smr[c*NPIX + p];
        float si = smi[c*NPIX + p];
        re += cr[c]*sr + ci[c]*si;
        im += ci[c]*sr - cr[c]*si;
    }
    out[p] = sqrtf(re*re + im*im);
}

__global__ __launch_bounds__(256) void adj_fallback(
    const float* __restrict__ kr, const float* __restrict__ ki,
    const float* __restrict__ traj, const float* __restrict__ dc,
    const float* __restrict__ smr, const float* __restrict__ smi,
    float* __restrict__ out)
{
    const int p = blockIdx.x * 256 + threadIdx.x;
    const float gx = (float)(p / NXY - NXY/2);
    const float gy = (float)(p % NXY - NXY/2);
    float ar[NC], ai[NC];
#pragma unroll
    for (int c = 0; c < NC; ++c) { ar[c] = 0.f; ai[c] = 0.f; }
    for (int m = 0; m < M_TOT; ++m) {
        float kx = traj[m];
        float ky = traj[M_TOT + m];
        float d  = dc[m];
        float ph = fmaf(kx, gx, ky * gy);
        float r  = __builtin_amdgcn_fractf(ph * INV2PI);
        float s = __builtin_amdgcn_sinf(r);
        float c = __builtin_amdgcn_cosf(r);
#pragma unroll
        for (int cc = 0; cc < NC; ++cc) {
            float wr = kr[cc*M_TOT + m] * d;
            float wi = ki[cc*M_TOT + m] * d;
            ar[cc] = fmaf(wr, c, fmaf(-wi, s, ar[cc]));
            ai[cc] = fmaf(wr, s, fmaf( wi, c, ai[cc]));
        }
    }
    float re = 0.f, im = 0.f;
#pragma unroll
    for (int c = 0; c < NC; ++c) {
        float sr = smr[c*NPIX + p];
        float si = smi[c*NPIX + p];
        re += ar[c]*sr + ai[c]*si;
        im += ai[c]*sr - ar[c]*si;
    }
    out[p] = sqrtf(re*re + im*im);
}

// ---------------------------------------------------------------------------
extern "C" void kernel_launch(void* const* d_in, const int* in_sizes, int n_in,
                              void* d_out, int out_size, void* d_ws, size_t ws_size,
                              hipStream_t stream)
{
    const float* kr   = (const float*)d_in[0];
    const float* ki   = (const float*)d_in[1];
    const float* traj = (const float*)d_in[2];
    const float* smr  = (const float*)d_in[3];
    const float* smi  = (const float*)d_in[4];
    const float* dc   = (const float*)d_in[5];
    float* out = (float*)d_out;

    const size_t B_bytes = (size_t)GN * GK * sizeof(fp16);            // 12.58 MB
    const size_t P_bytes = (size_t)KSPLIT * GM * GN * sizeof(fp16);   // 37.75 MB
    const size_t need_mfma = B_bytes + P_bytes;                       // ~50.3 MB

    if (ws_size >= need_mfma) {
        fp16* BT = (fp16*)d_ws;
        fp16* P  = (fp16*)((char*)d_ws + B_bytes);
        pack_B_mfma<<<(NXY*M_TOT)/256, 256, 0, stream>>>(traj, BT);
        gemm_fused<<<(GM/BM)*KSPLIT, 512, 0, stream>>>(kr, ki, dc, traj, BT, P);
        combine2<<<NPIX/256, 256, 0, stream>>>(P, smr, smi, out);
        return;
    }

    const size_t pack_bytes = (size_t)M_TOT * REC * sizeof(float);
    int split = 0;
    for (int s = 32; s >= 8; s >>= 1) {
        size_t need = pack_bytes + (size_t)s * NC * NPIX * 2 * sizeof(float);
        if (ws_size >= need) { split = s; break; }
    }
    if (split > 0) {
        float* pack    = (float*)d_ws;
        float* partial = pack + (size_t)M_TOT * REC;
        int mch = M_TOT / split;
        pack_kernel<<<(M_TOT + 255)/256, 256, 0, stream>>>(kr, ki, traj, dc, pack);
        adj_main<<<dim3(NPIX/2/256, split), 256, 0, stream>>>(pack, partial, mch);
        combine_kernel<<<NPIX/256, 256, 0, stream>>>(partial, smr, smi, out, split);
    } else {
        adj_fallback<<<NPIX/256, 256, 0, stream>>>(kr, ki, traj, dc, smr, smi, out);
    }
}

// Round 15
// 124.045 us; speedup vs baseline: 1.5802x; 1.0384x over previous
//
#include <hip/hip_runtime.h>
#include <math.h>

// Problem constants (B=1 hardcoded).
#define M_TOT 8192
#define NXY   192
#define NPIX  (192*192)   // 36864
#define NC    8
#define REC   20          // floats per packed record (fp32 fallback path)

// GEMM: C[r=(y*8+c), n'=2x+{re,im}] = sum_k' A[r,k'] B[k',n']
//   A[r, 2m+{0,1}] = Re/Im( (kspace*dc)[c,m] * Ey[m,y] )  -- fused in-kernel
//   BT[n'][k']: row 2x = (cos,-sin)(kx*gx); row 2x+1 = (sin,cos)(kx*gx)
#define GM 1536
#define GN 384
#define GK 16384
#define KSPLIT 32
#define KCHUNK (GK/KSPLIT)   // 512 k' = 256 m
#define BK 64                // k' per LDS step (32 m)
#define NSTEP (KCHUNK/BK)    // 8
#define BM 64                // 8 y * 8 c rows per tile
#define LDK 72               // padded LDS row stride (halves)

typedef _Float16 fp16;
typedef fp16 f16x8 __attribute__((ext_vector_type(8)));
typedef float f32x4 __attribute__((ext_vector_type(4)));

#define INV2PI 0.15915494309189535f

// ---------------------------------------------------------------------------
// pack_B: BT[n'=2x+e][k'=2m+g]  (fp16 row-major, k fastest) — proven R7-R13.
// ---------------------------------------------------------------------------
__global__ __launch_bounds__(256) void pack_B_mfma(
    const float* __restrict__ traj, fp16* __restrict__ BT)
{
    int tid = blockIdx.x * 256 + threadIdx.x;   // 192*8192
    int x = tid >> 13;
    int m = tid & 8191;
    float kx = traj[m];
    float gx = (float)(x - 96);
    float r  = __builtin_amdgcn_fractf(kx * gx * INV2PI);
    float s  = __builtin_amdgcn_sinf(r);
    float c  = __builtin_amdgcn_cosf(r);
    unsigned int* B2 = (unsigned int*)BT;
    union { fp16 h[2]; unsigned int u; } p0, p1;
    p0.h[0] = (fp16)c;  p0.h[1] = (fp16)(-s);   // row 2x:   (c, -s)
    p1.h[0] = (fp16)s;  p1.h[1] = (fp16)c;      // row 2x+1: (s,  c)
    B2[(size_t)x * GK + m]          = p0.u;
    B2[(size_t)x * GK + (GK/2) + m] = p1.u;
}

// ---------------------------------------------------------------------------
// gemm_fused: BM=64 x BN=384 (full N), A computed in-kernel into LDS.
// grid = 768 (24 tm x 32 kz), 512 threads (8 waves, 2m x 4n).
// R13-proven: phase-local staging (no cross-barrier register liveness) ->
// no scratch spill (WRITE_SIZE == pure P). UNCHANGED this round.
// ---------------------------------------------------------------------------
__global__ __launch_bounds__(512) void gemm_fused(
    const float* __restrict__ kr, const float* __restrict__ ki,
    const float* __restrict__ dc, const float* __restrict__ traj,
    const fp16* __restrict__ BT, fp16* __restrict__ P)
{
    __shared__ __align__(16) fp16 a_s[BM][LDK];   //  9.2 KB
    __shared__ __align__(16) fp16 b_s[GN][LDK];   // 55.3 KB  (total 63 KB -> 2 blocks/CU)

    const int bid = blockIdx.x;
    const int u   = bid & 7;
    const int j   = bid >> 3;          // 0..95
    const int kz  = u + 8 * (j & 3);   // 0..31; same kz -> same XCD
    const int tm  = j >> 2;            // 0..23
    const int t   = threadIdx.x;

    // --- B staging: 6 x 16B segments per thread per step
    const int brow0 = t >> 3;          // 0..63
    const int bseg  = t & 7;           // 0..7
    const fp16* pB = BT + (size_t)kz * KCHUNK + bseg * 8;

    // --- A producer: threads t<256 -> (yl = t>>5 in 0..7, ml = t&31)
    const int yl = t >> 5;
    const int ml = t & 31;
    const bool aprod = (t < 256);
    const float gy = (float)(tm * 8 + yl - 96);

    // --- MFMA mapping (conventions proven since R7)
    const int w_ = t >> 6, wm = w_ >> 2, wn = w_ & 3;   // 2m x 4n waves
    const int lane = t & 63, lr = lane & 15, lk = lane >> 4;

    f32x4 acc[2][6] = {};

    for (int step = 0; step < NSTEP; ++step) {
        __syncthreads();            // previous step's LDS reads complete

        // ---- B stage: load global -> reg -> LDS, all within this phase ----
        {
            uint4 breg[6];
#pragma unroll
            for (int i = 0; i < 6; ++i) {
                int rrow = i * 64 + brow0;
                breg[i] = *(const uint4*)(pB + (size_t)rrow * GK + step * BK);
            }
#pragma unroll
            for (int i = 0; i < 6; ++i) {
                int rrow = i * 64 + brow0;
                *(uint4*)&b_s[rrow][bseg * 8] = breg[i];
            }
        }

        // ---- A stage: produce (sincos + rotation) and write, same phase ----
        if (aprod) {
            int mg = kz * (KCHUNK/2) + step * (BK/2) + ml;   // global m
            float ky = traj[M_TOT + mg];
            float d  = dc[mg];
            float r  = __builtin_amdgcn_fractf(ky * gy * INV2PI);
            float sy = __builtin_amdgcn_sinf(r);
            float cy = __builtin_amdgcn_cosf(r);
#pragma unroll
            for (int c = 0; c < NC; ++c) {
                float wr = kr[c * M_TOT + mg] * d;
                float wi = ki[c * M_TOT + mg] * d;
                union { fp16 h[2]; unsigned int u; } pk;
                pk.h[0] = (fp16)(wr * cy - wi * sy);   // Re(w*Ey)
                pk.h[1] = (fp16)(wr * sy + wi * cy);   // Im(w*Ey)
                *(unsigned int*)&a_s[yl * 8 + c][2 * ml] = pk.u;
            }
        }

        __syncthreads();            // LDS tile visible

        // ---- MFMA cluster (register-only besides LDS fragment reads) ----
#pragma unroll
        for (int kk = 0; kk < 2; ++kk) {
            const int ko = kk * 32 + lk * 8;
            f16x8 af[2];
#pragma unroll
            for (int mi = 0; mi < 2; ++mi)
                af[mi] = *(const f16x8*)&a_s[wm * 32 + mi * 16 + lr][ko];
#pragma unroll
            for (int nj = 0; nj < 6; ++nj) {
                f16x8 bf = *(const f16x8*)&b_s[wn * 96 + nj * 16 + lr][ko];
#pragma unroll
                for (int mi = 0; mi < 2; ++mi)
                    acc[mi][nj] = __builtin_amdgcn_mfma_f32_16x16x32_f16(
                        af[mi], bf, acc[mi][nj], 0, 0, 0);
            }
        }
    }

    // ---- epilogue: f32 acc -> f16 partials ----
    fp16* Pz = P + (size_t)kz * GM * GN;
#pragma unroll
    for (int mi = 0; mi < 2; ++mi)
#pragma unroll
        for (int nj = 0; nj < 6; ++nj) {
            const int gcol = wn * 96 + nj * 16 + lr;
#pragma unroll
            for (int reg = 0; reg < 4; ++reg) {
                const int grow = tm * 64 + wm * 32 + mi * 16 + lk * 4 + reg;
                Pz[(size_t)grow * GN + gcol] = (fp16)acc[mi][nj][reg];
            }
        }
}

// ---------------------------------------------------------------------------
// reduce_kz: Q[r][x] = sum_kz P[kz][r][2x..2x+1]  (f32x2 out, 2.36 MB)
// R13 lesson: the old single combine kernel had 144 blocks (0.56/CU) doing
// 256 loads/thread -> latency-bound on a half-idle GPU. This stage uses
// 1152 blocks (4.5/CU), coalesced 768B row reads.
// ---------------------------------------------------------------------------
__global__ __launch_bounds__(256) void reduce_kz(
    const fp16* __restrict__ P, float2* __restrict__ Q)
{
    const int id = blockIdx.x * 256 + threadIdx.x;  // GM*192 = 294912
    const unsigned int* P32 = (const unsigned int*)P;
    float re = 0.f, im = 0.f;
#pragma unroll
    for (int kz = 0; kz < KSPLIT; ++kz) {
        union { unsigned int u; fp16 h[2]; } v;
        v.u = P32[(size_t)kz * (GM * GN / 2) + id];
        re += (float)v.h[0];
        im += (float)v.h[1];
    }
    Q[id] = make_float2(re, im);
}

// ---------------------------------------------------------------------------
// combine3: coil-combine with conj(smaps), magnitude. Reads reduced Q.
// 16x16 tiles, x lane-fast (proven combine2 indexing, 8 Q loads/thread).
// ---------------------------------------------------------------------------
__global__ __launch_bounds__(256) void combine3(
    const float2* __restrict__ Q,
    const float* __restrict__ smr, const float* __restrict__ smi,
    float* __restrict__ out)
{
    const int bid = blockIdx.x;                 // 144
    const int x = (bid % 12) * 16 + (threadIdx.x & 15);
    const int y = (bid / 12) * 16 + (threadIdx.x >> 4);

    float ore = 0.f, oim = 0.f;
#pragma unroll
    for (int c = 0; c < NC; ++c) {
        float2 v = Q[(y * 8 + c) * (GN/2) + x];
        float sr = smr[c * NPIX + x * NXY + y];
        float si = smi[c * NPIX + x * NXY + y];
        ore += v.x * sr + v.y * si;             // * conj(smap)
        oim += v.y * sr - v.x * si;
    }
    out[x * NXY + y] = sqrtf(ore * ore + oim * oim);
}

// ===========================================================================
// fp32 fallback path (proven @328us) — used only if ws too small.
// ===========================================================================
__global__ __launch_bounds__(256) void pack_kernel(
    const float* __restrict__ kr, const float* __restrict__ ki,
    const float* __restrict__ traj, const float* __restrict__ dc,
    float* __restrict__ pack)
{
    int m = blockIdx.x * 256 + threadIdx.x;
    if (m >= M_TOT) return;
    float d = dc[m];
    float* r = pack + (size_t)m * REC;
#pragma unroll
    for (int c = 0; c < NC; ++c) {
        r[2*c]   = kr[c*M_TOT + m] * d;
        r[2*c+1] = ki[c*M_TOT + m] * d;
    }
    float ky = traj[M_TOT + m];
    r[16] = traj[m];
    r[17] = ky;
    r[18] = cosf(ky);
    r[19] = sinf(ky);
}

__global__ __launch_bounds__(256) void adj_main(
    const float* __restrict__ pack, float* __restrict__ partial, int mch)
{
    const int t = blockIdx.x * 256 + threadIdx.x;
    const int split = blockIdx.y;
    const int p0 = t * 2;
    const float gx  = (float)(p0 / NXY - NXY/2);
    const float gy0 = (float)(p0 % NXY - NXY/2);

    float2 par[NC], pai[NC];
#pragma unroll
    for (int c = 0; c < NC; ++c) {
        par[c] = make_float2(0.f, 0.f);
        pai[c] = make_float2(0.f, 0.f);
    }
    const float* rec = pack + (size_t)split * mch * REC;
    for (int m = 0; m < mch; ++m, rec += REC) {
        const float4* r4 = (const float4*)rec;
        float4 w01 = r4[0], w23 = r4[1], w45 = r4[2], w67 = r4[3], tkk = r4[4];
        float ph = fmaf(tkk.x, gx, tkk.y * gy0);
        float r  = __builtin_amdgcn_fractf(ph * INV2PI);
        float s0 = __builtin_amdgcn_sinf(r);
        float c0 = __builtin_amdgcn_cosf(r);
        float c1 = fmaf(c0, tkk.z, -(s0 * tkk.w));
        float s1 = fmaf(s0, tkk.z,  (c0 * tkk.w));
#define COIL(WR, WI, IDX)                                                \
        par[IDX].x = fmaf((WR), c0, fmaf(-(WI), s0, par[IDX].x));        \
        par[IDX].y = fmaf((WR), c1, fmaf(-(WI), s1, par[IDX].y));        \
        pai[IDX].x = fmaf((WR), s0, fmaf( (WI), c0, pai[IDX].x));        \
        pai[IDX].y = fmaf((WR), s1, fmaf( (WI), c1, pai[IDX].y));
        COIL(w01.x, w01.y, 0) COIL(w01.z, w01.w, 1)
        COIL(w23.x, w23.y, 2) COIL(w23.z, w23.w, 3)
        COIL(w45.x, w45.y, 4) COIL(w45.z, w45.w, 5)
        COIL(w67.x, w67.y, 6) COIL(w67.z, w67.w, 7)
#undef COIL
    }
#pragma unroll
    for (int c = 0; c < NC; ++c) {
        float4 v = make_float4(par[c].x, pai[c].x, par[c].y, pai[c].y);
        *(float4*)(partial + ((size_t)(split*NC + c)*NPIX + p0)*2) = v;
    }
}

__global__ __launch_bounds__(256) void combine_kernel(
    const float* __restrict__ partial,
    const float* __restrict__ smr, const float* __restrict__ smi,
    float* __restrict__ out, int nsplit)
{
    const int p = blockIdx.x * 256 + threadIdx.x;
    float cr[NC], ci[NC];
#pragma unroll
    for (int c = 0; c < NC; ++c) { cr[c] = 0.f; ci[c] = 0.f; }
    for (int s = 0; s < nsplit; ++s)
#pragma unroll
        for (int c = 0; c < NC; ++c) {
            float2 v = *(const float2*)(partial + ((size_t)(s*NC + c)*NPIX + p)*2);
            cr[c] += v.x; ci[c] += v.y;
        }
    float re = 0.f, im = 0.f;
#pragma unroll
    for (int c = 0; c < NC; ++c) {
        float sr = smr[c*NPIX + p];
        float si = smi[c*NPIX + p];
        re += cr[c]*sr + ci[c]*si;
        im += ci[c]*sr - cr[c]*si;
    }
    out[p] = sqrtf(re*re + im*im);
}

__global__ __launch_bounds__(256) void adj_fallback(
    const float* __restrict__ kr, const float* __restrict__ ki,
    const float* __restrict__ traj, const float* __restrict__ dc,
    const float* __restrict__ smr, const float* __restrict__ smi,
    float* __restrict__ out)
{
    const int p = blockIdx.x * 256 + threadIdx.x;
    const float gx = (float)(p / NXY - NXY/2);
    const float gy = (float)(p % NXY - NXY/2);
    float ar[NC], ai[NC];
#pragma unroll
    for (int c = 0; c < NC; ++c) { ar[c] = 0.f; ai[c] = 0.f; }
    for (int m = 0; m < M_TOT; ++m) {
        float kx = traj[m];
        float ky = traj[M_TOT + m];
        float d  = dc[m];
        float ph = fmaf(kx, gx, ky * gy);
        float r  = __builtin_amdgcn_fractf(ph * INV2PI);
        float s = __builtin_amdgcn_sinf(r);
        float c = __builtin_amdgcn_cosf(r);
#pragma unroll
        for (int cc = 0; cc < NC; ++cc) {
            float wr = kr[cc*M_TOT + m] * d;
            float wi = ki[cc*M_TOT + m] * d;
            ar[cc] = fmaf(wr, c, fmaf(-wi, s, ar[cc]));
            ai[cc] = fmaf(wr, s, fmaf( wi, c, ai[cc]));
        }
    }
    float re = 0.f, im = 0.f;
#pragma unroll
    for (int c = 0; c < NC; ++c) {
        float sr = smr[c*NPIX + p];
        float si = smi[c*NPIX + p];
        re += ar[c]*sr + ai[c]*si;
        im += ai[c]*sr - ar[c]*si;
    }
    out[p] = sqrtf(re*re + im*im);
}

// ---------------------------------------------------------------------------
extern "C" void kernel_launch(void* const* d_in, const int* in_sizes, int n_in,
                              void* d_out, int out_size, void* d_ws, size_t ws_size,
                              hipStream_t stream)
{
    const float* kr   = (const float*)d_in[0];
    const float* ki   = (const float*)d_in[1];
    const float* traj = (const float*)d_in[2];
    const float* smr  = (const float*)d_in[3];
    const float* smi  = (const float*)d_in[4];
    const float* dc   = (const float*)d_in[5];
    float* out = (float*)d_out;

    const size_t B_bytes = (size_t)GN * GK * sizeof(fp16);            // 12.58 MB
    const size_t P_bytes = (size_t)KSPLIT * GM * GN * sizeof(fp16);   // 37.75 MB
    const size_t Q_bytes = (size_t)GM * (GN/2) * sizeof(float2);      //  2.36 MB
    const size_t need_mfma = B_bytes + P_bytes + Q_bytes;             // ~52.7 MB

    if (ws_size >= need_mfma) {
        fp16*   BT = (fp16*)d_ws;
        fp16*   P  = (fp16*)((char*)d_ws + B_bytes);
        float2* Q  = (float2*)((char*)d_ws + B_bytes + P_bytes);
        pack_B_mfma<<<(NXY*M_TOT)/256, 256, 0, stream>>>(traj, BT);
        gemm_fused<<<(GM/BM)*KSPLIT, 512, 0, stream>>>(kr, ki, dc, traj, BT, P);
        reduce_kz<<<(GM*(GN/2))/256, 256, 0, stream>>>(P, Q);
        combine3<<<NPIX/256, 256, 0, stream>>>(Q, smr, smi, out);
        return;
    }

    const size_t pack_bytes = (size_t)M_TOT * REC * sizeof(float);
    int split = 0;
    for (int s = 32; s >= 8; s >>= 1) {
        size_t need = pack_bytes + (size_t)s * NC * NPIX * 2 * sizeof(float);
        if (ws_size >= need) { split = s; break; }
    }
    if (split > 0) {
        float* pack    = (float*)d_ws;
        float* partial = pack + (size_t)M_TOT * REC;
        int mch = M_TOT / split;
        pack_kernel<<<(M_TOT + 255)/256, 256, 0, stream>>>(kr, ki, traj, dc, pack);
        adj_main<<<dim3(NPIX/2/256, split), 256, 0, stream>>>(pack, partial, mch);
        combine_kernel<<<NPIX/256, 256, 0, stream>>>(partial, smr, smi, out, split);
    } else {
        adj_fallback<<<NPIX/256, 256, 0, stream>>>(kr, ki, traj, dc, smr, smi, out);
    }
}